// Round 7
// baseline (87.441 us; speedup 1.0000x reference)
//
#include <hip/hip_runtime.h>
#include <hip/hip_bf16.h>

#define NR 4096
#define DIM 1024
#define NCLS 512

typedef __attribute__((ext_vector_type(4))) float f32x4;
typedef __attribute__((ext_vector_type(8))) int v8i;

// fp4 e2m1 quantizer: values {0,.5,1,1.5,2,3,4,6}, round-to-nearest, saturate.
static __device__ __forceinline__ unsigned int q4(float v) {
  unsigned int s = (v < 0.f) ? 8u : 0u;
  float a = fabsf(v);
  unsigned int c;
  if (a < 0.25f) c = 0;
  else if (a < 0.75f) c = 1;
  else if (a < 1.25f) c = 2;
  else if (a < 1.75f) c = 3;
  else if (a < 2.5f) c = 4;
  else if (a < 3.5f) c = 5;
  else if (a < 5.0f) c = 6;
  else c = 7;
  return s | c;
}

// ---- kernel 1: fused prep -------------------------------------------------
// blocks 0..1023   : row norms -> fp4 e2m1 normalized copy (x32), packed
// blocks 1024..2047: CE per row (4 rows/block)
// block 2048       : label stats (cnt, fpos via min1/min2), zero slot0/out
// fp4 layout per row (512 B): 8 K-chunks of 64 B; within a chunk, group
// g=(k>>5)&3 occupies bytes [g*16, g*16+16), element k at byte (k&31)>>1,
// nibble k&1. So the 16 B at g*16 is exactly one MFMA fragment (k-block g).
__global__ __launch_bounds__(256) void k_prep(const float* __restrict__ x,
                                              const int* __restrict__ y,
                                              const float* __restrict__ yp,
                                              unsigned char* __restrict__ xnp,
                                              int* __restrict__ cnt,
                                              int* __restrict__ fpos,
                                              float* __restrict__ slot0,
                                              float* __restrict__ ce,
                                              float* __restrict__ out) {
  const int b = blockIdx.x;
  const int tid = threadIdx.x;
  if (b < 1024) {
    int row = b * 4 + (tid >> 6);
    int lane = tid & 63;
    const float4* xr = reinterpret_cast<const float4*>(x + (size_t)row * DIM);
    float4 v[4];
    float s = 0.f;
#pragma unroll
    for (int it = 0; it < 4; ++it) {
      v[it] = xr[it * 64 + lane];
      s += v[it].x * v[it].x + v[it].y * v[it].y + v[it].z * v[it].z + v[it].w * v[it].w;
    }
#pragma unroll
    for (int d = 1; d < 64; d <<= 1) s += __shfl_xor(s, d);
    float inv = 32.0f / fmaxf(sqrtf(s), 1e-8f);  // fold SCALE=32 (exact pow2)
    unsigned char* xo = xnp + (size_t)row * 512;
#pragma unroll
    for (int it = 0; it < 4; ++it) {
      int k0 = (it * 64 + lane) * 4;  // quad start, 4-aligned, within one group
      int pos = (k0 >> 7) * 64 + ((k0 >> 5) & 3) * 16 + ((k0 & 31) >> 1);
      unsigned int n0 = q4(v[it].x * inv), n1 = q4(v[it].y * inv),
                   n2 = q4(v[it].z * inv), n3 = q4(v[it].w * inv);
      unsigned short pk =
          (unsigned short)(n0 | (n1 << 4) | (n2 << 8) | (n3 << 12));
      *(unsigned short*)(xo + pos) = pk;
    }
  } else if (b < 2048) {
    int row = (b - 1024) * 4 + (tid >> 6);
    int lane = tid & 63;
    const float4* p = reinterpret_cast<const float4*>(yp + (size_t)row * NCLS);
    float4 v0 = p[lane], v1 = p[lane + 64];
    float m = fmaxf(fmaxf(fmaxf(v0.x, v0.y), fmaxf(v0.z, v0.w)),
                    fmaxf(fmaxf(v1.x, v1.y), fmaxf(v1.z, v1.w)));
#pragma unroll
    for (int d = 1; d < 64; d <<= 1) m = fmaxf(m, __shfl_xor(m, d));
    float s = __expf(v0.x - m) + __expf(v0.y - m) + __expf(v0.z - m) + __expf(v0.w - m) +
              __expf(v1.x - m) + __expf(v1.y - m) + __expf(v1.z - m) + __expf(v1.w - m);
#pragma unroll
    for (int d = 1; d < 64; d <<= 1) s += __shfl_xor(s, d);
    if (lane == 0) {
      float py = yp[(size_t)row * NCLS + y[row]];
      ce[row] = logf(s) + m - py;
    }
  } else {
    __shared__ int ys[NR];
    __shared__ int scnt[NCLS], sm1[NCLS], sm2[NCLS];
    for (int j = tid; j < NR; j += 256) ys[j] = y[j];
    for (int c = tid; c < NCLS; c += 256) { scnt[c] = 0; sm1[c] = NR; sm2[c] = NR; }
    __syncthreads();
    for (int i = tid; i < NR; i += 256) {
      int c = ys[i];
      atomicAdd(&scnt[c], 1);
      atomicMin(&sm1[c], i);
    }
    __syncthreads();
    for (int i = tid; i < NR; i += 256) {
      int c = ys[i];
      if (sm1[c] != i) atomicMin(&sm2[c], i);
    }
    __syncthreads();
    for (int i = tid; i < NR; i += 256) {
      int c = ys[i];
      int m1 = sm1[c];
      int j = (m1 == i) ? ((sm2[c] >= NR) ? -1 : sm2[c]) : m1;
      fpos[i] = j;
      slot0[i] = 0.f;
    }
    for (int c = tid; c < NCLS; c += 256) cnt[c] = scnt[c];
    if (tid == 0) out[0] = 0.f;
  }
}

// ---- kernel 2: 8-phase 256x256 MX-fp4 MFMA GEMM + fused masked-exp epilogue
// mfma_scale_f32_16x16x128_f8f6f4, fmt A=B=4 (fp4 e2m1), scales 0x7F (=1.0).
// LDS: 2 bufs x {A0,A1,B0,B1} 8KB half-tiles (128 rows x 64 B = K-chunk 128),
// 64KB total. Bank swizzle: phys = logical ^ ((row & 3) << 4), row = byte>>6
// (involution). Dest linear for global_load_lds; source pre-inverse-swizzled;
// ds_read swizzled. One b128 = one full fp4 fragment (payload v[0:3]).
// 8 K-chunks of 128 -> 4 iterations x 8 phases (same validated schedule:
// ph0:A0(t1)->b1 ph1:A1(t1)->b1 ph2:B0(tn0)->b0 ph3:B1(tn0)->b0 [vmcnt2]
// ph4:A0(tn0)->b0 ph5:A1(tn0)->b0 ph6:B0(tn1)->b1 ph7:B1(tn1)->b1 [vmcnt2]).

#define STAGE(SSLOT, GROWBASE, KT)                                               \
  {                                                                              \
    const char* _src = (const char*)xnp +                                        \
        (size_t)((GROWBASE) + srow) * 512 + (size_t)(KT) * 64 + scol;            \
    __builtin_amdgcn_global_load_lds(                                            \
        (const __attribute__((address_space(1))) void*)_src,                     \
        (__attribute__((address_space(3))) void*)(lds + (SSLOT) + (w << 10)),    \
        16, 0, 0);                                                               \
  }

#define PHASE(BUFB, MF0, LOADB, SSLOT, SBASE, SKT, VM)                           \
  {                                                                              \
    _Pragma("unroll") for (int mm = 0; mm < 2; ++mm) {                           \
      int4 t4 = *(const int4*)(lds + (BUFB) + ABaseW +                           \
                               ((MF0) + mm) * 1024 + kread);                     \
      v8i tv = {t4.x, t4.y, t4.z, t4.w, 0, 0, 0, 0};                             \
      afr[mm] = tv;                                                              \
    }                                                                            \
    if (LOADB) {                                                                 \
      _Pragma("unroll") for (int nf = 0; nf < 4; ++nf) {                         \
        int4 t4 = *(const int4*)(lds + (BUFB) + BBaseW + nf * 1024 + kread);     \
        v8i tv = {t4.x, t4.y, t4.z, t4.w, 0, 0, 0, 0};                           \
        bfr[nf] = tv;                                                            \
      }                                                                          \
    }                                                                            \
    STAGE(SSLOT, SBASE, SKT)                                                     \
    if (VM) asm volatile("s_waitcnt vmcnt(2)" ::: "memory");                     \
    __builtin_amdgcn_s_barrier();                                                \
    asm volatile("s_waitcnt lgkmcnt(0)" ::: "memory");                           \
    __builtin_amdgcn_sched_barrier(0);                                           \
    __builtin_amdgcn_s_setprio(1);                                               \
    _Pragma("unroll") for (int mm = 0; mm < 2; ++mm)                             \
      _Pragma("unroll") for (int nf = 0; nf < 4; ++nf)                           \
        acc[(MF0) + mm][nf] = __builtin_amdgcn_mfma_scale_f32_16x16x128_f8f6f4(  \
            afr[mm], bfr[nf], acc[(MF0) + mm][nf], 4, 4,                         \
            0, 0x7F7F7F7F, 0, 0x7F7F7F7F);                                       \
    __builtin_amdgcn_s_setprio(0);                                               \
    __builtin_amdgcn_sched_barrier(0);                                           \
    __builtin_amdgcn_s_barrier();                                                \
  }

__global__ __launch_bounds__(512, 2) void k_gemm(const unsigned char* __restrict__ xnp,
                                                 const int* __restrict__ y,
                                                 const int* __restrict__ fpos,
                                                 float* __restrict__ part,
                                                 float* __restrict__ slot0) {
  __shared__ char lds[65536];
  const int tid = threadIdx.x;
  const int w = tid >> 6, lane = tid & 63;
  const int wr = w >> 2, wcn = w & 3;
  const int r0 = lane & 15, klo = lane >> 4;

  const int bid = blockIdx.x;
  const int swzb = (bid & 7) * 32 + (bid >> 3);  // XCD swizzle, 256%8==0 ok
  const int rb = swzb >> 4, cb = swzb & 15;
  const int rowbase = rb * 256, colbase = cb * 256;

  const int kread = (klo * 16) ^ ((r0 & 3) << 4);
  const int ABaseW = wr * 8192 + r0 * 64;
  const int BBaseW = 16384 + (wcn >> 1) * 8192 + (wcn & 1) * 4096 + r0 * 64;

  int srow, scol;
  {
    int D = tid * 16;                          // linear dest in half-tile
    int L = D ^ (((D >> 6) & 3) << 4);         // inverse swizzle (involution)
    srow = L >> 6;
    scol = L & 63;
  }

  f32x4 acc[8][4] = {};

  // prologue: K-chunk 0 -> buf0 fully; B halves of K-chunk 1 -> buf1
  STAGE(0, rowbase, 0)
  STAGE(8192, rowbase + 128, 0)
  STAGE(16384, colbase, 0)
  STAGE(24576, colbase + 128, 0)
  STAGE(32768 + 16384, colbase, 1)
  STAGE(32768 + 24576, colbase + 128, 1)
  asm volatile("s_waitcnt vmcnt(2)" ::: "memory");
  __builtin_amdgcn_s_barrier();

  for (int i = 0; i < 4; ++i) {
    const int t1 = 2 * i + 1;
    const int tn0 = (2 * i + 2 < 8) ? 2 * i + 2 : 7;  // clamped dead-slot
    const int tn1 = (2 * i + 3 < 8) ? 2 * i + 3 : 7;  // stages keep counts
    v8i afr[2], bfr[4];
    PHASE(0, 0, 1, 32768, rowbase, t1, 0)
    PHASE(0, 2, 0, 32768 + 8192, rowbase + 128, t1, 0)
    PHASE(0, 4, 0, 16384, colbase, tn0, 0)
    PHASE(0, 6, 0, 24576, colbase + 128, tn0, 1)
    PHASE(32768, 0, 1, 0, rowbase, tn0, 0)
    PHASE(32768, 2, 0, 8192, rowbase + 128, tn0, 0)
    PHASE(32768, 4, 0, 32768 + 16384, colbase, tn1, 0)
    PHASE(32768, 6, 0, 32768 + 24576, colbase + 128, tn1, 1)
  }

  // drain in-flight stages before repurposing LDS
  asm volatile("s_waitcnt vmcnt(0)" ::: "memory");
  __syncthreads();

  // ---- epilogue: masked exp row-sums + slot0 scatter ----
  // sim = acc/1024 (SCALE=32 squared), sv = (sim+1)*0.25 = acc/4096 + 0.25
  int* yrow_s = (int*)lds;            // 256 ints
  int* ycol_s = (int*)(lds + 1024);   // 256 ints
  int* frow_s = (int*)(lds + 2048);   // 256 ints
  float* rsum = (float*)(lds + 4096); // 256*4 floats
  if (tid < 256) {
    yrow_s[tid] = y[rowbase + tid];
    frow_s[tid] = fpos[rowbase + tid];
  } else {
    ycol_s[tid - 256] = y[colbase + tid - 256];
  }
  __syncthreads();

  const int g = klo;
#pragma unroll
  for (int mf = 0; mf < 8; ++mf) {
    float rs[4] = {0.f, 0.f, 0.f, 0.f};
    int rloc[4], yr[4], fr[4];
#pragma unroll
    for (int reg = 0; reg < 4; ++reg) {
      rloc[reg] = wr * 128 + mf * 16 + g * 4 + reg;
      yr[reg] = yrow_s[rloc[reg]];
      fr[reg] = frow_s[rloc[reg]];
    }
#pragma unroll
    for (int nf = 0; nf < 4; ++nf) {
      int cl = wcn * 64 + nf * 16 + r0;
      int yc = ycol_s[cl];
      int gc = colbase + cl;
#pragma unroll
      for (int reg = 0; reg < 4; ++reg) {
        float sv = acc[mf][nf][reg] * (1.0f / 4096.f) + 0.25f;
        float e = (yr[reg] == yc) ? 0.f : __expf(sv);
        rs[reg] += e;
        if (fr[reg] == gc) slot0[rowbase + rloc[reg]] = sv;
      }
    }
#pragma unroll
    for (int d = 1; d < 16; d <<= 1)
#pragma unroll
      for (int reg = 0; reg < 4; ++reg) rs[reg] += __shfl_xor(rs[reg], d);
    if (r0 == 0) {
#pragma unroll
      for (int reg = 0; reg < 4; ++reg)
        rsum[rloc[reg] * 4 + wcn] = rs[reg];
    }
  }
  __syncthreads();
  if (tid < 256)
    part[(size_t)cb * NR + rowbase + tid] =
        rsum[tid * 4] + rsum[tid * 4 + 1] + rsum[tid * 4 + 2] + rsum[tid * 4 + 3];
}

// ---- kernel 3: final loss reduction ----------------------------------------
__global__ __launch_bounds__(256) void k_final(const float* __restrict__ part,
                                               const float* __restrict__ slot0,
                                               const int* __restrict__ cnt,
                                               const int* __restrict__ y,
                                               const float* __restrict__ ce,
                                               float* __restrict__ out) {
  __shared__ float red[256];
  const int tid = threadIdx.x;
  const int r = blockIdx.x * 256 + tid;
  float S = 0.f;
#pragma unroll
  for (int b = 0; b < 16; ++b) S += part[(size_t)b * NR + r];
  float s0 = slot0[r];
  float zeros = 4094.0f + (float)cnt[y[r]];  // 8190 - (4096 - cnt)
  float cl = logf(__expf(s0) + S + zeros) - s0;
  red[tid] = 0.5f * (cl + ce[r]);
  __syncthreads();
  for (int s = 128; s > 0; s >>= 1) {
    if (tid < s) red[tid] += red[tid + s];
    __syncthreads();
  }
  if (tid == 0) atomicAdd(out, red[0] / (float)NR);
}

extern "C" void kernel_launch(void* const* d_in, const int* in_sizes, int n_in,
                              void* d_out, int out_size, void* d_ws, size_t ws_size,
                              hipStream_t stream) {
  const float* x = (const float*)d_in[0];
  const int* y = (const int*)d_in[1];
  const float* yp = (const float*)d_in[2];
  float* out = (float*)d_out;

  char* w = (char*)d_ws;
  unsigned char* xnp = (unsigned char*)w;    // 4096*512 = 2097152 B
  int* cnt = (int*)(w + 2097152);            // 2048 B
  int* fpos = (int*)(w + 2099200);           // 16384 B
  float* slot0 = (float*)(w + 2115584);      // 16384 B
  float* part = (float*)(w + 2131968);       // 16*4096*4 = 262144 B
  float* ce = (float*)(w + 2394112);         // 16384 B

  k_prep<<<2049, 256, 0, stream>>>(x, y, yp, xnp, cnt, fpos, slot0, ce, out);
  k_gemm<<<256, 512, 0, stream>>>(xnp, y, fpos, part, slot0);
  k_final<<<16, 256, 0, stream>>>(part, slot0, cnt, y, ce, out);
}

// Round 8
// 87.276 us; speedup vs baseline: 1.0019x; 1.0019x over previous
//
#include <hip/hip_runtime.h>
#include <hip/hip_bf16.h>

#define NR 4096
#define DIM 1024
#define NCLS 512

typedef __attribute__((ext_vector_type(4))) float f32x4;
typedef __attribute__((ext_vector_type(8))) int v8i;

// fp4 e2m1 quantizer: values {0,.5,1,1.5,2,3,4,6}, round-to-nearest, saturate.
static __device__ __forceinline__ unsigned int q4(float v) {
  unsigned int s = (v < 0.f) ? 8u : 0u;
  float a = fabsf(v);
  unsigned int c;
  if (a < 0.25f) c = 0;
  else if (a < 0.75f) c = 1;
  else if (a < 1.25f) c = 2;
  else if (a < 1.75f) c = 3;
  else if (a < 2.5f) c = 4;
  else if (a < 3.5f) c = 5;
  else if (a < 5.0f) c = 6;
  else c = 7;
  return s | c;
}

// ---- kernel 1: fused prep -------------------------------------------------
// blocks 0..1023   : row norms -> fp4 e2m1 normalized copy (x32), packed
// blocks 1024..2047: CE per row (4 rows/block)
// block 2048       : label stats (cnt, fpos via min1/min2), zero slot0/out
// fp4 layout per row (512 B): 8 K-chunks of 64 B; within a chunk, group
// g=(k>>5)&3 occupies bytes [g*16, g*16+16), element k at byte (k&31)>>1,
// nibble k&1. So the 16 B at g*16 is exactly one MFMA fragment (k-block g).
__global__ __launch_bounds__(256) void k_prep(const float* __restrict__ x,
                                              const int* __restrict__ y,
                                              const float* __restrict__ yp,
                                              unsigned char* __restrict__ xnp,
                                              int* __restrict__ cnt,
                                              int* __restrict__ fpos,
                                              float* __restrict__ slot0,
                                              float* __restrict__ ce,
                                              float* __restrict__ out) {
  const int b = blockIdx.x;
  const int tid = threadIdx.x;
  if (b < 1024) {
    int row = b * 4 + (tid >> 6);
    int lane = tid & 63;
    const float4* xr = reinterpret_cast<const float4*>(x + (size_t)row * DIM);
    float4 v[4];
    float s = 0.f;
#pragma unroll
    for (int it = 0; it < 4; ++it) {
      v[it] = xr[it * 64 + lane];
      s += v[it].x * v[it].x + v[it].y * v[it].y + v[it].z * v[it].z + v[it].w * v[it].w;
    }
#pragma unroll
    for (int d = 1; d < 64; d <<= 1) s += __shfl_xor(s, d);
    float inv = 32.0f / fmaxf(sqrtf(s), 1e-8f);  // fold SCALE=32 (exact pow2)
    unsigned char* xo = xnp + (size_t)row * 512;
#pragma unroll
    for (int it = 0; it < 4; ++it) {
      int k0 = (it * 64 + lane) * 4;  // quad start, 4-aligned, within one group
      int pos = (k0 >> 7) * 64 + ((k0 >> 5) & 3) * 16 + ((k0 & 31) >> 1);
      unsigned int n0 = q4(v[it].x * inv), n1 = q4(v[it].y * inv),
                   n2 = q4(v[it].z * inv), n3 = q4(v[it].w * inv);
      unsigned short pk =
          (unsigned short)(n0 | (n1 << 4) | (n2 << 8) | (n3 << 12));
      *(unsigned short*)(xo + pos) = pk;
    }
  } else if (b < 2048) {
    int row = (b - 1024) * 4 + (tid >> 6);
    int lane = tid & 63;
    const float4* p = reinterpret_cast<const float4*>(yp + (size_t)row * NCLS);
    float4 v0 = p[lane], v1 = p[lane + 64];
    float m = fmaxf(fmaxf(fmaxf(v0.x, v0.y), fmaxf(v0.z, v0.w)),
                    fmaxf(fmaxf(v1.x, v1.y), fmaxf(v1.z, v1.w)));
#pragma unroll
    for (int d = 1; d < 64; d <<= 1) m = fmaxf(m, __shfl_xor(m, d));
    float s = __expf(v0.x - m) + __expf(v0.y - m) + __expf(v0.z - m) + __expf(v0.w - m) +
              __expf(v1.x - m) + __expf(v1.y - m) + __expf(v1.z - m) + __expf(v1.w - m);
#pragma unroll
    for (int d = 1; d < 64; d <<= 1) s += __shfl_xor(s, d);
    if (lane == 0) {
      float py = yp[(size_t)row * NCLS + y[row]];
      ce[row] = logf(s) + m - py;
    }
  } else {
    __shared__ int ys[NR];
    __shared__ int scnt[NCLS], sm1[NCLS], sm2[NCLS];
    for (int j = tid; j < NR; j += 256) ys[j] = y[j];
    for (int c = tid; c < NCLS; c += 256) { scnt[c] = 0; sm1[c] = NR; sm2[c] = NR; }
    __syncthreads();
    for (int i = tid; i < NR; i += 256) {
      int c = ys[i];
      atomicAdd(&scnt[c], 1);
      atomicMin(&sm1[c], i);
    }
    __syncthreads();
    for (int i = tid; i < NR; i += 256) {
      int c = ys[i];
      if (sm1[c] != i) atomicMin(&sm2[c], i);
    }
    __syncthreads();
    for (int i = tid; i < NR; i += 256) {
      int c = ys[i];
      int m1 = sm1[c];
      int j = (m1 == i) ? ((sm2[c] >= NR) ? -1 : sm2[c]) : m1;
      fpos[i] = j;
      slot0[i] = 0.f;
    }
    for (int c = tid; c < NCLS; c += 256) cnt[c] = scnt[c];
    if (tid == 0) out[0] = 0.f;
  }
}

// ---- kernel 2: 8-phase 256x256 MX-fp4 MFMA GEMM + fused masked-exp epilogue
// mfma_scale_f32_16x16x128_f8f6f4, fmt A=B=4 (fp4 e2m1), scales 0x7F (=1.0).
// LDS: 2 bufs x {A0,A1,B0,B1} 8KB half-tiles (128 rows x 64 B = K-chunk 128),
// 64KB total. Bank swizzle: phys = logical ^ ((row & 3) << 4), row = byte>>6
// (involution). Dest linear for global_load_lds; source pre-inverse-swizzled;
// ds_read swizzled. One b128 = one full fp4 fragment (payload v[0:3]).
// 8 K-chunks of 128 -> 4 iterations x 8 phases.
// launch_bounds (512,1): fp4 operands are 8-VGPR tuples (afr+bfr = 48 regs);
// with (512,2)'s 128-VGPR cap the 128-reg accumulator spilled to scratch
// (R7: 91 MB FETCH+WRITE, 2x regression). Grid=256=#CUs -> 1 block/CU anyway.

#define STAGE(SSLOT, GROWBASE, KT)                                               \
  {                                                                              \
    const char* _src = (const char*)xnp +                                        \
        (size_t)((GROWBASE) + srow) * 512 + (size_t)(KT) * 64 + scol;            \
    __builtin_amdgcn_global_load_lds(                                            \
        (const __attribute__((address_space(1))) void*)_src,                     \
        (__attribute__((address_space(3))) void*)(lds + (SSLOT) + (w << 10)),    \
        16, 0, 0);                                                               \
  }

#define PHASE(BUFB, MF0, LOADB, SSLOT, SBASE, SKT, VM)                           \
  {                                                                              \
    _Pragma("unroll") for (int mm = 0; mm < 2; ++mm) {                           \
      int4 t4 = *(const int4*)(lds + (BUFB) + ABaseW +                           \
                               ((MF0) + mm) * 1024 + kread);                     \
      v8i tv = {t4.x, t4.y, t4.z, t4.w, 0, 0, 0, 0};                             \
      afr[mm] = tv;                                                              \
    }                                                                            \
    if (LOADB) {                                                                 \
      _Pragma("unroll") for (int nf = 0; nf < 4; ++nf) {                         \
        int4 t4 = *(const int4*)(lds + (BUFB) + BBaseW + nf * 1024 + kread);     \
        v8i tv = {t4.x, t4.y, t4.z, t4.w, 0, 0, 0, 0};                           \
        bfr[nf] = tv;                                                            \
      }                                                                          \
    }                                                                            \
    STAGE(SSLOT, SBASE, SKT)                                                     \
    if (VM) asm volatile("s_waitcnt vmcnt(2)" ::: "memory");                     \
    __builtin_amdgcn_s_barrier();                                                \
    asm volatile("s_waitcnt lgkmcnt(0)" ::: "memory");                           \
    __builtin_amdgcn_sched_barrier(0);                                           \
    __builtin_amdgcn_s_setprio(1);                                               \
    _Pragma("unroll") for (int mm = 0; mm < 2; ++mm)                             \
      _Pragma("unroll") for (int nf = 0; nf < 4; ++nf)                           \
        acc[(MF0) + mm][nf] = __builtin_amdgcn_mfma_scale_f32_16x16x128_f8f6f4(  \
            afr[mm], bfr[nf], acc[(MF0) + mm][nf], 4, 4,                         \
            0, 0x7F7F7F7F, 0, 0x7F7F7F7F);                                       \
    __builtin_amdgcn_s_setprio(0);                                               \
    __builtin_amdgcn_sched_barrier(0);                                           \
    __builtin_amdgcn_s_barrier();                                                \
  }

__global__ __launch_bounds__(512, 1) void k_gemm(const unsigned char* __restrict__ xnp,
                                                 const int* __restrict__ y,
                                                 const int* __restrict__ fpos,
                                                 float* __restrict__ part,
                                                 float* __restrict__ slot0) {
  __shared__ char lds[65536];
  const int tid = threadIdx.x;
  const int w = tid >> 6, lane = tid & 63;
  const int wr = w >> 2, wcn = w & 3;
  const int r0 = lane & 15, klo = lane >> 4;

  const int bid = blockIdx.x;
  const int swzb = (bid & 7) * 32 + (bid >> 3);  // XCD swizzle, 256%8==0 ok
  const int rb = swzb >> 4, cb = swzb & 15;
  const int rowbase = rb * 256, colbase = cb * 256;

  const int kread = (klo * 16) ^ ((r0 & 3) << 4);
  const int ABaseW = wr * 8192 + r0 * 64;
  const int BBaseW = 16384 + (wcn >> 1) * 8192 + (wcn & 1) * 4096 + r0 * 64;

  int srow, scol;
  {
    int D = tid * 16;                          // linear dest in half-tile
    int L = D ^ (((D >> 6) & 3) << 4);         // inverse swizzle (involution)
    srow = L >> 6;
    scol = L & 63;
  }

  f32x4 acc[8][4] = {};

  // prologue: K-chunk 0 -> buf0 fully; B halves of K-chunk 1 -> buf1
  STAGE(0, rowbase, 0)
  STAGE(8192, rowbase + 128, 0)
  STAGE(16384, colbase, 0)
  STAGE(24576, colbase + 128, 0)
  STAGE(32768 + 16384, colbase, 1)
  STAGE(32768 + 24576, colbase + 128, 1)
  asm volatile("s_waitcnt vmcnt(2)" ::: "memory");
  __builtin_amdgcn_s_barrier();

  for (int i = 0; i < 4; ++i) {
    const int t1 = 2 * i + 1;
    const int tn0 = (2 * i + 2 < 8) ? 2 * i + 2 : 7;  // clamped dead-slot
    const int tn1 = (2 * i + 3 < 8) ? 2 * i + 3 : 7;  // stages keep counts
    v8i afr[2], bfr[4];
    PHASE(0, 0, 1, 32768, rowbase, t1, 0)
    PHASE(0, 2, 0, 32768 + 8192, rowbase + 128, t1, 0)
    PHASE(0, 4, 0, 16384, colbase, tn0, 0)
    PHASE(0, 6, 0, 24576, colbase + 128, tn0, 1)
    PHASE(32768, 0, 1, 0, rowbase, tn0, 0)
    PHASE(32768, 2, 0, 8192, rowbase + 128, tn0, 0)
    PHASE(32768, 4, 0, 32768 + 16384, colbase, tn1, 0)
    PHASE(32768, 6, 0, 32768 + 24576, colbase + 128, tn1, 1)
  }

  // drain in-flight stages before repurposing LDS
  asm volatile("s_waitcnt vmcnt(0)" ::: "memory");
  __syncthreads();

  // ---- epilogue: masked exp row-sums + slot0 scatter ----
  // sim = acc/1024 (SCALE=32 squared), sv = (sim+1)*0.25 = acc/4096 + 0.25
  int* yrow_s = (int*)lds;            // 256 ints
  int* ycol_s = (int*)(lds + 1024);   // 256 ints
  int* frow_s = (int*)(lds + 2048);   // 256 ints
  float* rsum = (float*)(lds + 4096); // 256*4 floats
  if (tid < 256) {
    yrow_s[tid] = y[rowbase + tid];
    frow_s[tid] = fpos[rowbase + tid];
  } else {
    ycol_s[tid - 256] = y[colbase + tid - 256];
  }
  __syncthreads();

  const int g = klo;
#pragma unroll
  for (int mf = 0; mf < 8; ++mf) {
    float rs[4] = {0.f, 0.f, 0.f, 0.f};
    int rloc[4], yr[4], fr[4];
#pragma unroll
    for (int reg = 0; reg < 4; ++reg) {
      rloc[reg] = wr * 128 + mf * 16 + g * 4 + reg;
      yr[reg] = yrow_s[rloc[reg]];
      fr[reg] = frow_s[rloc[reg]];
    }
#pragma unroll
    for (int nf = 0; nf < 4; ++nf) {
      int cl = wcn * 64 + nf * 16 + r0;
      int yc = ycol_s[cl];
      int gc = colbase + cl;
#pragma unroll
      for (int reg = 0; reg < 4; ++reg) {
        float sv = acc[mf][nf][reg] * (1.0f / 4096.f) + 0.25f;
        float e = (yr[reg] == yc) ? 0.f : __expf(sv);
        rs[reg] += e;
        if (fr[reg] == gc) slot0[rowbase + rloc[reg]] = sv;
      }
    }
#pragma unroll
    for (int d = 1; d < 16; d <<= 1)
#pragma unroll
      for (int reg = 0; reg < 4; ++reg) rs[reg] += __shfl_xor(rs[reg], d);
    if (r0 == 0) {
#pragma unroll
      for (int reg = 0; reg < 4; ++reg)
        rsum[rloc[reg] * 4 + wcn] = rs[reg];
    }
  }
  __syncthreads();
  if (tid < 256)
    part[(size_t)cb * NR + rowbase + tid] =
        rsum[tid * 4] + rsum[tid * 4 + 1] + rsum[tid * 4 + 2] + rsum[tid * 4 + 3];
}

// ---- kernel 3: final loss reduction ----------------------------------------
__global__ __launch_bounds__(256) void k_final(const float* __restrict__ part,
                                               const float* __restrict__ slot0,
                                               const int* __restrict__ cnt,
                                               const int* __restrict__ y,
                                               const float* __restrict__ ce,
                                               float* __restrict__ out) {
  __shared__ float red[256];
  const int tid = threadIdx.x;
  const int r = blockIdx.x * 256 + tid;
  float S = 0.f;
#pragma unroll
  for (int b = 0; b < 16; ++b) S += part[(size_t)b * NR + r];
  float s0 = slot0[r];
  float zeros = 4094.0f + (float)cnt[y[r]];  // 8190 - (4096 - cnt)
  float cl = logf(__expf(s0) + S + zeros) - s0;
  red[tid] = 0.5f * (cl + ce[r]);
  __syncthreads();
  for (int s = 128; s > 0; s >>= 1) {
    if (tid < s) red[tid] += red[tid + s];
    __syncthreads();
  }
  if (tid == 0) atomicAdd(out, red[0] / (float)NR);
}

extern "C" void kernel_launch(void* const* d_in, const int* in_sizes, int n_in,
                              void* d_out, int out_size, void* d_ws, size_t ws_size,
                              hipStream_t stream) {
  const float* x = (const float*)d_in[0];
  const int* y = (const int*)d_in[1];
  const float* yp = (const float*)d_in[2];
  float* out = (float*)d_out;

  char* w = (char*)d_ws;
  unsigned char* xnp = (unsigned char*)w;    // 4096*512 = 2097152 B
  int* cnt = (int*)(w + 2097152);            // 2048 B
  int* fpos = (int*)(w + 2099200);           // 16384 B
  float* slot0 = (float*)(w + 2115584);      // 16384 B
  float* part = (float*)(w + 2131968);       // 16*4096*4 = 262144 B
  float* ce = (float*)(w + 2394112);         // 16384 B

  k_prep<<<2049, 256, 0, stream>>>(x, y, yp, xnp, cnt, fpos, slot0, ce, out);
  k_gemm<<<256, 512, 0, stream>>>(xnp, y, fpos, part, slot0);
  k_final<<<16, 256, 0, stream>>>(part, slot0, cnt, y, ce, out);
}

// Round 9
// 48.119 us; speedup vs baseline: 1.8172x; 1.8137x over previous
//
#include <hip/hip_runtime.h>
#include <hip/hip_bf16.h>

#define NR 4096
#define DIM 1024
#define NCLS 512

typedef __attribute__((ext_vector_type(4))) float f32x4;
typedef __attribute__((ext_vector_type(8))) int v8i;

// fp4 e2m1 quantizer: values {0,.5,1,1.5,2,3,4,6}, round-to-nearest, saturate.
static __device__ __forceinline__ unsigned int q4(float v) {
  unsigned int s = (v < 0.f) ? 8u : 0u;
  float a = fabsf(v);
  unsigned int c;
  if (a < 0.25f) c = 0;
  else if (a < 0.75f) c = 1;
  else if (a < 1.25f) c = 2;
  else if (a < 1.75f) c = 3;
  else if (a < 2.5f) c = 4;
  else if (a < 3.5f) c = 5;
  else if (a < 5.0f) c = 6;
  else c = 7;
  return s | c;
}

// ---- kernel 1: fused prep (unchanged from R7, numerics validated) ----------
__global__ __launch_bounds__(256) void k_prep(const float* __restrict__ x,
                                              const int* __restrict__ y,
                                              const float* __restrict__ yp,
                                              unsigned char* __restrict__ xnp,
                                              int* __restrict__ cnt,
                                              int* __restrict__ fpos,
                                              float* __restrict__ slot0,
                                              float* __restrict__ ce,
                                              float* __restrict__ out) {
  const int b = blockIdx.x;
  const int tid = threadIdx.x;
  if (b < 1024) {
    int row = b * 4 + (tid >> 6);
    int lane = tid & 63;
    const float4* xr = reinterpret_cast<const float4*>(x + (size_t)row * DIM);
    float4 v[4];
    float s = 0.f;
#pragma unroll
    for (int it = 0; it < 4; ++it) {
      v[it] = xr[it * 64 + lane];
      s += v[it].x * v[it].x + v[it].y * v[it].y + v[it].z * v[it].z + v[it].w * v[it].w;
    }
#pragma unroll
    for (int d = 1; d < 64; d <<= 1) s += __shfl_xor(s, d);
    float inv = 32.0f / fmaxf(sqrtf(s), 1e-8f);  // fold SCALE=32 (exact pow2)
    unsigned char* xo = xnp + (size_t)row * 512;
#pragma unroll
    for (int it = 0; it < 4; ++it) {
      int k0 = (it * 64 + lane) * 4;  // quad start, 4-aligned, within one group
      int pos = (k0 >> 7) * 64 + ((k0 >> 5) & 3) * 16 + ((k0 & 31) >> 1);
      unsigned int n0 = q4(v[it].x * inv), n1 = q4(v[it].y * inv),
                   n2 = q4(v[it].z * inv), n3 = q4(v[it].w * inv);
      unsigned short pk =
          (unsigned short)(n0 | (n1 << 4) | (n2 << 8) | (n3 << 12));
      *(unsigned short*)(xo + pos) = pk;
    }
  } else if (b < 2048) {
    int row = (b - 1024) * 4 + (tid >> 6);
    int lane = tid & 63;
    const float4* p = reinterpret_cast<const float4*>(yp + (size_t)row * NCLS);
    float4 v0 = p[lane], v1 = p[lane + 64];
    float m = fmaxf(fmaxf(fmaxf(v0.x, v0.y), fmaxf(v0.z, v0.w)),
                    fmaxf(fmaxf(v1.x, v1.y), fmaxf(v1.z, v1.w)));
#pragma unroll
    for (int d = 1; d < 64; d <<= 1) m = fmaxf(m, __shfl_xor(m, d));
    float s = __expf(v0.x - m) + __expf(v0.y - m) + __expf(v0.z - m) + __expf(v0.w - m) +
              __expf(v1.x - m) + __expf(v1.y - m) + __expf(v1.z - m) + __expf(v1.w - m);
#pragma unroll
    for (int d = 1; d < 64; d <<= 1) s += __shfl_xor(s, d);
    if (lane == 0) {
      float py = yp[(size_t)row * NCLS + y[row]];
      ce[row] = logf(s) + m - py;
    }
  } else {
    __shared__ int ys[NR];
    __shared__ int scnt[NCLS], sm1[NCLS], sm2[NCLS];
    for (int j = tid; j < NR; j += 256) ys[j] = y[j];
    for (int c = tid; c < NCLS; c += 256) { scnt[c] = 0; sm1[c] = NR; sm2[c] = NR; }
    __syncthreads();
    for (int i = tid; i < NR; i += 256) {
      int c = ys[i];
      atomicAdd(&scnt[c], 1);
      atomicMin(&sm1[c], i);
    }
    __syncthreads();
    for (int i = tid; i < NR; i += 256) {
      int c = ys[i];
      if (sm1[c] != i) atomicMin(&sm2[c], i);
    }
    __syncthreads();
    for (int i = tid; i < NR; i += 256) {
      int c = ys[i];
      int m1 = sm1[c];
      int j = (m1 == i) ? ((sm2[c] >= NR) ? -1 : sm2[c]) : m1;
      fpos[i] = j;
      slot0[i] = 0.f;
    }
    for (int c = tid; c < NCLS; c += 256) cnt[c] = scnt[c];
    if (tid == 0) out[0] = 0.f;
  }
}

// ---- kernel 2: 4-phase 128x128 MX-fp4 MFMA GEMM + fused masked-exp epilogue
// Register-budget redesign (R7/R8 spilled: acc128+ops48 > 128-VGPR cap):
// per-wave output 64x32 -> acc[4][2]=32 regs; afr[2]+bfr[2]=32; total ~110.
// LDS 32KB: 2 bufs x {A(8KB),B(8KB)}; 1024 blocks -> 2 blocks/CU.
// Schedule (iter i, t0=2i in buf0, t1=2i+1 in buf1), stages 1 gload each:
//   p0 reads buf0 rows01+B, stage A(t1)->b1A
//   p1 reads buf0 rows23,   stage B(t0+2)->b0B, vmcnt(1)  [protects p2]
//   p2 reads buf1 rows01+B, stage A(t0+2)->b0A
//   p3 reads buf1 rows23,   stage B(t1+2)->b1B, vmcnt(1)  [protects next p0]
// Every staged slot's last read ended >=1 barrier before the stage; tail
// clamps to chunk 7 (dead stages keep vmcnt counts uniform).

#define STAGE(SSLOT, GROWBASE, KT)                                               \
  {                                                                              \
    const char* _src = (const char*)xnp +                                        \
        (size_t)((GROWBASE) + srow) * 512 + (size_t)(KT) * 64 + scol;            \
    __builtin_amdgcn_global_load_lds(                                            \
        (const __attribute__((address_space(1))) void*)_src,                     \
        (__attribute__((address_space(3))) void*)(lds + (SSLOT) + tid * 16),     \
        16, 0, 0);                                                               \
  }

#define PHASE(BUFB, RP, LOADB, SSLOT, SBASE, SKT, VM)                            \
  {                                                                              \
    _Pragma("unroll") for (int mm = 0; mm < 2; ++mm) {                           \
      int4 t4 = *(const int4*)(lds + (BUFB) + ABaseW +                           \
                               ((RP) * 2 + mm) * 1024);                          \
      v8i tv = {t4.x, t4.y, t4.z, t4.w, 0, 0, 0, 0};                             \
      afr[mm] = tv;                                                              \
    }                                                                            \
    if (LOADB) {                                                                 \
      _Pragma("unroll") for (int nf = 0; nf < 2; ++nf) {                         \
        int4 t4 = *(const int4*)(lds + (BUFB) + BBaseW + nf * 1024);             \
        v8i tv = {t4.x, t4.y, t4.z, t4.w, 0, 0, 0, 0};                           \
        bfr[nf] = tv;                                                            \
      }                                                                          \
    }                                                                            \
    STAGE(SSLOT, SBASE, SKT)                                                     \
    if (VM) asm volatile("s_waitcnt vmcnt(1)" ::: "memory");                     \
    __builtin_amdgcn_s_barrier();                                                \
    asm volatile("s_waitcnt lgkmcnt(0)" ::: "memory");                           \
    __builtin_amdgcn_sched_barrier(0);                                           \
    __builtin_amdgcn_s_setprio(1);                                               \
    _Pragma("unroll") for (int mm = 0; mm < 2; ++mm)                             \
      _Pragma("unroll") for (int nf = 0; nf < 2; ++nf)                           \
        acc[(RP) * 2 + mm][nf] = __builtin_amdgcn_mfma_scale_f32_16x16x128_f8f6f4( \
            afr[mm], bfr[nf], acc[(RP) * 2 + mm][nf], 4, 4,                      \
            0, 0x7F7F7F7F, 0, 0x7F7F7F7F);                                       \
    __builtin_amdgcn_s_setprio(0);                                               \
    __builtin_amdgcn_sched_barrier(0);                                           \
    __builtin_amdgcn_s_barrier();                                                \
  }

__global__ __launch_bounds__(512, 2) void k_gemm(const unsigned char* __restrict__ xnp,
                                                 const int* __restrict__ y,
                                                 const int* __restrict__ fpos,
                                                 float* __restrict__ part,
                                                 float* __restrict__ slot0) {
  __shared__ char lds[32768];
  const int tid = threadIdx.x;
  const int w = tid >> 6, lane = tid & 63;
  const int wr = w >> 2, wcn = w & 3;
  const int r0 = lane & 15, klo = lane >> 4;

  const int bid = blockIdx.x;
  const int swzb = (bid & 7) * 128 + (bid >> 3);  // XCD swizzle, 1024%8==0 ok
  const int rb = swzb >> 5, cb = swzb & 31;
  const int rowbase = rb * 128, colbase = cb * 128;

  const int kread = (klo * 16) ^ ((r0 & 3) << 4);
  const int ABaseW = wr * 4096 + r0 * 64 + kread;
  const int BBaseW = 8192 + wcn * 2048 + r0 * 64 + kread;

  int srow, scol;
  {
    int D = tid * 16;                          // linear dest in tile
    int L = D ^ (((D >> 6) & 3) << 4);         // inverse swizzle (involution)
    srow = L >> 6;
    scol = L & 63;
  }

  f32x4 acc[4][2] = {};

  // prologue: A(0),B(0) -> buf0; B(1) -> buf1-B
  STAGE(8192, colbase, 0)           // B(0) -> b0B
  STAGE(0, rowbase, 0)              // A(0) -> b0A
  STAGE(24576, colbase, 1)          // B(1) -> b1B
  asm volatile("s_waitcnt vmcnt(1)" ::: "memory");
  __builtin_amdgcn_s_barrier();

  for (int i = 0; i < 4; ++i) {
    const int t1 = 2 * i + 1;
    const int tn = (2 * i + 2 < 8) ? 2 * i + 2 : 7;   // clamped dead-slot
    const int tn1 = (2 * i + 3 < 8) ? 2 * i + 3 : 7;  // stages keep counts
    v8i afr[2], bfr[2];
    PHASE(0,     0, 1, 16384, rowbase, t1, 0)   // p0
    PHASE(0,     1, 0, 8192,  colbase, tn, 1)   // p1
    PHASE(16384, 0, 1, 0,     rowbase, tn, 0)   // p2
    PHASE(16384, 1, 0, 24576, colbase, tn1, 1)  // p3
  }

  // drain in-flight stages before repurposing LDS
  asm volatile("s_waitcnt vmcnt(0)" ::: "memory");
  __syncthreads();

  // ---- epilogue: masked exp row-sums + slot0 scatter ----
  // sim = acc/1024 (SCALE=32 squared), sv = (sim+1)*0.25 = acc/4096 + 0.25
  int* yrow_s = (int*)lds;            // 128 ints
  int* ycol_s = (int*)(lds + 512);    // 128 ints
  int* frow_s = (int*)(lds + 1024);   // 128 ints
  float* rsum = (float*)(lds + 2048); // 128*4 floats
  if (tid < 128) {
    yrow_s[tid] = y[rowbase + tid];
    frow_s[tid] = fpos[rowbase + tid];
  } else if (tid < 256) {
    ycol_s[tid - 128] = y[colbase + tid - 128];
  }
  __syncthreads();

#pragma unroll
  for (int m = 0; m < 4; ++m) {
    float rs[4] = {0.f, 0.f, 0.f, 0.f};
    int rloc[4], yr[4], fr[4];
#pragma unroll
    for (int reg = 0; reg < 4; ++reg) {
      rloc[reg] = wr * 64 + m * 16 + klo * 4 + reg;
      yr[reg] = yrow_s[rloc[reg]];
      fr[reg] = frow_s[rloc[reg]];
    }
#pragma unroll
    for (int nf = 0; nf < 2; ++nf) {
      int cl = wcn * 32 + nf * 16 + r0;
      int yc = ycol_s[cl];
      int gc = colbase + cl;
#pragma unroll
      for (int reg = 0; reg < 4; ++reg) {
        float sv = acc[m][nf][reg] * (1.0f / 4096.f) + 0.25f;
        float e = (yr[reg] == yc) ? 0.f : __expf(sv);
        rs[reg] += e;
        if (fr[reg] == gc) slot0[rowbase + rloc[reg]] = sv;
      }
    }
#pragma unroll
    for (int d = 1; d < 16; d <<= 1)
#pragma unroll
      for (int reg = 0; reg < 4; ++reg) rs[reg] += __shfl_xor(rs[reg], d);
    if (r0 == 0) {
#pragma unroll
      for (int reg = 0; reg < 4; ++reg)
        rsum[rloc[reg] * 4 + wcn] = rs[reg];
    }
  }
  __syncthreads();
  if (tid < 128)
    part[(size_t)cb * NR + rowbase + tid] =
        rsum[tid * 4] + rsum[tid * 4 + 1] + rsum[tid * 4 + 2] + rsum[tid * 4 + 3];
}

// ---- kernel 3: final loss reduction ----------------------------------------
__global__ __launch_bounds__(256) void k_final(const float* __restrict__ part,
                                               const float* __restrict__ slot0,
                                               const int* __restrict__ cnt,
                                               const int* __restrict__ y,
                                               const float* __restrict__ ce,
                                               float* __restrict__ out) {
  __shared__ float red[256];
  const int tid = threadIdx.x;
  const int r = blockIdx.x * 256 + tid;
  float S = 0.f;
#pragma unroll
  for (int b = 0; b < 32; ++b) S += part[(size_t)b * NR + r];
  float s0 = slot0[r];
  float zeros = 4094.0f + (float)cnt[y[r]];  // 8190 - (4096 - cnt)
  float cl = logf(__expf(s0) + S + zeros) - s0;
  red[tid] = 0.5f * (cl + ce[r]);
  __syncthreads();
  for (int s = 128; s > 0; s >>= 1) {
    if (tid < s) red[tid] += red[tid + s];
    __syncthreads();
  }
  if (tid == 0) atomicAdd(out, red[0] / (float)NR);
}

extern "C" void kernel_launch(void* const* d_in, const int* in_sizes, int n_in,
                              void* d_out, int out_size, void* d_ws, size_t ws_size,
                              hipStream_t stream) {
  const float* x = (const float*)d_in[0];
  const int* y = (const int*)d_in[1];
  const float* yp = (const float*)d_in[2];
  float* out = (float*)d_out;

  char* w = (char*)d_ws;
  unsigned char* xnp = (unsigned char*)w;    // 4096*512 = 2097152 B
  int* cnt = (int*)(w + 2097152);            // 2048 B
  int* fpos = (int*)(w + 2099200);           // 16384 B
  float* slot0 = (float*)(w + 2115584);      // 16384 B
  float* part = (float*)(w + 2131968);       // 32*4096*4 = 524288 B
  float* ce = (float*)(w + 2656256);         // 16384 B

  k_prep<<<2049, 256, 0, stream>>>(x, y, yp, xnp, cnt, fpos, slot0, ce, out);
  k_gemm<<<1024, 512, 0, stream>>>(xnp, y, fpos, part, slot0);
  k_final<<<16, 256, 0, stream>>>(part, slot0, cnt, y, ce, out);
}